// Round 1
// baseline (230.368 us; speedup 1.0000x reference)
//
#include <hip/hip_runtime.h>
#include <hip/hip_fp16.h>

#define T_TOK 1024
#define H_DIM 2048
#define I_DIM 1408
#define N_EXP 8
#define TOPK  2

using f16x8 = __attribute__((ext_vector_type(8))) _Float16;
using f32x4 = __attribute__((ext_vector_type(4))) float;

#define BM 128
#define BN 128
#define BK 32
#define LDSP 40  // padded K stride in halves (80 B = 20 banks -> <=2-way conflicts)

// ---------------- workspace layout (bytes) ----------------
#define WS_COUNTS      0
#define WS_BASES       256
#define WS_CURSORS     512
#define WS_TOPK_E      768                      // int[2048]
#define WS_TOPK_W      9216                     // float[2048]
#define WS_TOK_OF_SLOT 17664                    // int[2048]
#define WS_W_OF_SLOT   26112                    // float[2048]
#define WS_SLOT_OF_TOK 34560                    // int[2048]
#define WS_HACT        43008                    // f16[2048*1408] = 5767168 B
#define WS_Y           (43008 + 5767168)        // f32[2048*2048] = 16777216 B
#define WS_NEEDED      (WS_Y + 16777216)

// ---------------- router ----------------
__global__ void k_zero_counts(int* counts) {
    if (threadIdx.x < N_EXP) counts[threadIdx.x] = 0;
}

__global__ void k_router(const float* __restrict__ X, const float* __restrict__ GW,
                         int* __restrict__ counts, int* __restrict__ topk_e,
                         float* __restrict__ topk_w) {
    int t = (blockIdx.x * blockDim.x + threadIdx.x) >> 6;
    int lane = threadIdx.x & 63;
    if (t >= T_TOK) return;
    float acc[N_EXP];
#pragma unroll
    for (int e = 0; e < N_EXP; ++e) acc[e] = 0.f;
    const float* xrow = X + (size_t)t * H_DIM;
    for (int h = lane; h < H_DIM; h += 64) {
        float x = xrow[h];
        const float* g = GW + (size_t)h * N_EXP;
#pragma unroll
        for (int e = 0; e < N_EXP; ++e) acc[e] = fmaf(x, g[e], acc[e]);
    }
#pragma unroll
    for (int off = 32; off > 0; off >>= 1) {
#pragma unroll
        for (int e = 0; e < N_EXP; ++e) acc[e] += __shfl_xor(acc[e], off, 64);
    }
    if (lane == 0) {
        float m = acc[0];
#pragma unroll
        for (int e = 1; e < N_EXP; ++e) m = fmaxf(m, acc[e]);
        float ex[N_EXP], s = 0.f;
#pragma unroll
        for (int e = 0; e < N_EXP; ++e) { ex[e] = expf(acc[e] - m); s += ex[e]; }
        float inv = 1.f / s;
        int e1 = 0;
#pragma unroll
        for (int e = 1; e < N_EXP; ++e) if (ex[e] > ex[e1]) e1 = e;
        int e2 = (e1 == 0) ? 1 : 0;
#pragma unroll
        for (int e = 0; e < N_EXP; ++e) if (e != e1 && ex[e] > ex[e2]) e2 = e;
        topk_e[t * 2 + 0] = e1;
        topk_e[t * 2 + 1] = e2;
        topk_w[t * 2 + 0] = ex[e1] * inv;
        topk_w[t * 2 + 1] = ex[e2] * inv;
        atomicAdd(&counts[e1], 1);
        atomicAdd(&counts[e2], 1);
    }
}

__global__ void k_prefix(const int* __restrict__ counts, int* __restrict__ bases,
                         int* __restrict__ cursors) {
    if (threadIdx.x == 0) {
        int b = 0;
        for (int e = 0; e < N_EXP; ++e) { bases[e] = b; b += counts[e]; cursors[e] = 0; }
    }
}

__global__ void k_scatter(const int* __restrict__ topk_e, const float* __restrict__ topk_w,
                          const int* __restrict__ bases, int* __restrict__ cursors,
                          int* __restrict__ tok_of_slot, float* __restrict__ w_of_slot,
                          int* __restrict__ slot_of_tok) {
    int t = blockIdx.x * blockDim.x + threadIdx.x;
    if (t >= T_TOK) return;
    for (int j = 0; j < TOPK; ++j) {
        int e = topk_e[t * 2 + j];
        int pos = atomicAdd(&cursors[e], 1);
        int slot = bases[e] + pos;
        tok_of_slot[slot] = t;
        w_of_slot[slot] = topk_w[t * 2 + j];
        slot_of_tok[t * 2 + j] = slot;
    }
}

// ---------------- GEMM1: hact[slot, i] = silu(x[tok] . w1[e,:,i]) * w_slot ----------------
__global__ __launch_bounds__(256) void k_gemm1(
    const float* __restrict__ X, const float* __restrict__ W1,
    const int* __restrict__ counts, const int* __restrict__ bases,
    const int* __restrict__ tok_of_slot, const float* __restrict__ w_of_slot,
    _Float16* __restrict__ hact) {
    __shared__ _Float16 As[2][BM][LDSP];
    __shared__ _Float16 Bs[2][BN][LDSP];

    int e = blockIdx.z;
    int cnt = counts[e];
    int base = bases[e];
    int m0 = blockIdx.y * BM;
    if (m0 >= cnt) return;
    int n0 = blockIdx.x * BN;
    int tid = threadIdx.x;

    // A staging map: thread -> (row, 16-wide k chunk)
    int ar = tid >> 1;
    int akc = (tid & 1) * 16;
    int r_eff = min(ar, cnt - m0 - 1);
    int tok = tok_of_slot[base + m0 + r_eff];
    const float* arow = X + (size_t)tok * H_DIM;

    // B staging map: thread -> (col n, 16-row k chunk), transpose into Bs[n][k]
    int bn = tid & 127;
    int bkh = (tid >> 7) * 16;
    const float* w1e = W1 + (size_t)e * H_DIM * I_DIM;

    int wid = tid >> 6, lane = tid & 63;
    int wm = (wid >> 1) * 64, wn = (wid & 1) * 64;
    f32x4 acc[4][4] = {};

    auto stage = [&](int buf, int k0) {
        float av[16];
        *(float4*)(av + 0)  = *(const float4*)(arow + k0 + akc + 0);
        *(float4*)(av + 4)  = *(const float4*)(arow + k0 + akc + 4);
        *(float4*)(av + 8)  = *(const float4*)(arow + k0 + akc + 8);
        *(float4*)(av + 12) = *(const float4*)(arow + k0 + akc + 12);
        float bv[16];
#pragma unroll
        for (int j = 0; j < 16; ++j)
            bv[j] = w1e[(size_t)(k0 + bkh + j) * I_DIM + n0 + bn];
        f16x8 p0, p1, q0, q1;
#pragma unroll
        for (int j = 0; j < 8; ++j) {
            p0[j] = (_Float16)av[j];   p1[j] = (_Float16)av[j + 8];
            q0[j] = (_Float16)bv[j];   q1[j] = (_Float16)bv[j + 8];
        }
        *(f16x8*)&As[buf][ar][akc + 0] = p0;
        *(f16x8*)&As[buf][ar][akc + 8] = p1;
        *(f16x8*)&Bs[buf][bn][bkh + 0] = q0;
        *(f16x8*)&Bs[buf][bn][bkh + 8] = q1;
    };

    auto compute = [&](int buf) {
        int rsel = lane & 15, ksel = (lane >> 4) * 8;
        f16x8 af[4], bf[4];
#pragma unroll
        for (int i = 0; i < 4; ++i)
            af[i] = *(const f16x8*)&As[buf][wm + i * 16 + rsel][ksel];
#pragma unroll
        for (int j = 0; j < 4; ++j)
            bf[j] = *(const f16x8*)&Bs[buf][wn + j * 16 + rsel][ksel];
#pragma unroll
        for (int i = 0; i < 4; ++i)
#pragma unroll
            for (int j = 0; j < 4; ++j)
                acc[i][j] = __builtin_amdgcn_mfma_f32_16x16x32_f16(af[i], bf[j], acc[i][j], 0, 0, 0);
    };

    stage(0, 0);
    __syncthreads();
    const int KT = H_DIM / BK;
    for (int kt = 0; kt < KT; ++kt) {
        int cur = kt & 1;
        if (kt + 1 < KT) stage(cur ^ 1, (kt + 1) * BK);
        compute(cur);
        __syncthreads();
    }

    int rows = cnt - m0;
#pragma unroll
    for (int i = 0; i < 4; ++i) {
#pragma unroll
        for (int q = 0; q < 4; ++q) {
            int r = wm + i * 16 + (lane >> 4) * 4 + q;
            if (r < rows) {
                int slot = base + m0 + r;
                float w = w_of_slot[slot];
                _Float16* hrow = hact + (size_t)slot * I_DIM + n0;
#pragma unroll
                for (int j = 0; j < 4; ++j) {
                    float v = acc[i][j][q];
                    float s = v / (1.f + expf(-v)) * w;
                    hrow[wn + j * 16 + (lane & 15)] = (_Float16)s;
                }
            }
        }
    }
}

// ---------------- GEMM2: y[slot, h] = hact[slot, :] . w2[e, :, h] ----------------
__global__ __launch_bounds__(256) void k_gemm2(
    const _Float16* __restrict__ hact, const float* __restrict__ W2,
    const int* __restrict__ counts, const int* __restrict__ bases,
    float* __restrict__ y) {
    __shared__ _Float16 As[2][BM][LDSP];
    __shared__ _Float16 Bs[2][BN][LDSP];

    int e = blockIdx.z;
    int cnt = counts[e];
    int base = bases[e];
    int m0 = blockIdx.y * BM;
    if (m0 >= cnt) return;
    int n0 = blockIdx.x * BN;
    int tid = threadIdx.x;

    int ar = tid >> 1;
    int akc = (tid & 1) * 16;
    int r_eff = min(ar, cnt - m0 - 1);
    const _Float16* arow = hact + (size_t)(base + m0 + r_eff) * I_DIM;

    int bn = tid & 127;
    int bkh = (tid >> 7) * 16;
    const float* w2e = W2 + (size_t)e * I_DIM * H_DIM;

    int wid = tid >> 6, lane = tid & 63;
    int wm = (wid >> 1) * 64, wn = (wid & 1) * 64;
    f32x4 acc[4][4] = {};

    auto stage = [&](int buf, int k0) {
        f16x8 p0 = *(const f16x8*)(arow + k0 + akc + 0);
        f16x8 p1 = *(const f16x8*)(arow + k0 + akc + 8);
        float bv[16];
#pragma unroll
        for (int j = 0; j < 16; ++j)
            bv[j] = w2e[(size_t)(k0 + bkh + j) * H_DIM + n0 + bn];
        f16x8 q0, q1;
#pragma unroll
        for (int j = 0; j < 8; ++j) { q0[j] = (_Float16)bv[j]; q1[j] = (_Float16)bv[j + 8]; }
        *(f16x8*)&As[buf][ar][akc + 0] = p0;
        *(f16x8*)&As[buf][ar][akc + 8] = p1;
        *(f16x8*)&Bs[buf][bn][bkh + 0] = q0;
        *(f16x8*)&Bs[buf][bn][bkh + 8] = q1;
    };

    auto compute = [&](int buf) {
        int rsel = lane & 15, ksel = (lane >> 4) * 8;
        f16x8 af[4], bf[4];
#pragma unroll
        for (int i = 0; i < 4; ++i)
            af[i] = *(const f16x8*)&As[buf][wm + i * 16 + rsel][ksel];
#pragma unroll
        for (int j = 0; j < 4; ++j)
            bf[j] = *(const f16x8*)&Bs[buf][wn + j * 16 + rsel][ksel];
#pragma unroll
        for (int i = 0; i < 4; ++i)
#pragma unroll
            for (int j = 0; j < 4; ++j)
                acc[i][j] = __builtin_amdgcn_mfma_f32_16x16x32_f16(af[i], bf[j], acc[i][j], 0, 0, 0);
    };

    stage(0, 0);
    __syncthreads();
    const int KT = I_DIM / BK;
    for (int kt = 0; kt < KT; ++kt) {
        int cur = kt & 1;
        if (kt + 1 < KT) stage(cur ^ 1, (kt + 1) * BK);
        compute(cur);
        __syncthreads();
    }

    int rows = cnt - m0;
#pragma unroll
    for (int i = 0; i < 4; ++i) {
#pragma unroll
        for (int q = 0; q < 4; ++q) {
            int r = wm + i * 16 + (lane >> 4) * 4 + q;
            if (r < rows) {
                int slot = base + m0 + r;
                float* yrow = y + (size_t)slot * H_DIM + n0;
#pragma unroll
                for (int j = 0; j < 4; ++j)
                    yrow[wn + j * 16 + (lane & 15)] = acc[i][j][q];
            }
        }
    }
}

// ---------------- combine: out[t] = y[slotA] + y[slotB] ----------------
__global__ void k_combine(const float* __restrict__ y, const int* __restrict__ slot_of_tok,
                          float* __restrict__ out) {
    int t = blockIdx.x;
    int sA = slot_of_tok[t * 2 + 0];
    int sB = slot_of_tok[t * 2 + 1];
    const float4* ya = (const float4*)(y + (size_t)sA * H_DIM);
    const float4* yb = (const float4*)(y + (size_t)sB * H_DIM);
    float4* o = (float4*)(out + (size_t)t * H_DIM);
    for (int c = threadIdx.x; c < H_DIM / 4; c += blockDim.x) {
        float4 a = ya[c], b = yb[c];
        float4 r;
        r.x = a.x + b.x; r.y = a.y + b.y; r.z = a.z + b.z; r.w = a.w + b.w;
        o[c] = r;
    }
}

extern "C" void kernel_launch(void* const* d_in, const int* in_sizes, int n_in,
                              void* d_out, int out_size, void* d_ws, size_t ws_size,
                              hipStream_t stream) {
    const float* X  = (const float*)d_in[0];
    const float* GW = (const float*)d_in[1];
    const float* W1 = (const float*)d_in[2];
    const float* W2 = (const float*)d_in[3];
    float* out = (float*)d_out;
    char* ws = (char*)d_ws;
    if (ws_size < (size_t)WS_NEEDED) return;  // workspace too small: bail (will show as wrong output)

    int*   counts      = (int*)(ws + WS_COUNTS);
    int*   bases       = (int*)(ws + WS_BASES);
    int*   cursors     = (int*)(ws + WS_CURSORS);
    int*   topk_e      = (int*)(ws + WS_TOPK_E);
    float* topk_w      = (float*)(ws + WS_TOPK_W);
    int*   tok_of_slot = (int*)(ws + WS_TOK_OF_SLOT);
    float* w_of_slot   = (float*)(ws + WS_W_OF_SLOT);
    int*   slot_of_tok = (int*)(ws + WS_SLOT_OF_TOK);
    _Float16* hact     = (_Float16*)(ws + WS_HACT);
    float* y           = (float*)(ws + WS_Y);

    k_zero_counts<<<1, 64, 0, stream>>>(counts);
    k_router<<<T_TOK / 4, 256, 0, stream>>>(X, GW, counts, topk_e, topk_w);
    k_prefix<<<1, 64, 0, stream>>>(counts, bases, cursors);
    k_scatter<<<T_TOK / 256, 256, 0, stream>>>(topk_e, topk_w, bases, cursors,
                                               tok_of_slot, w_of_slot, slot_of_tok);
    k_gemm1<<<dim3(I_DIM / BN, T_TOK / BM, N_EXP), 256, 0, stream>>>(
        X, W1, counts, bases, tok_of_slot, w_of_slot, hact);
    k_gemm2<<<dim3(H_DIM / BN, T_TOK / BM, N_EXP), 256, 0, stream>>>(
        hact, W2, counts, bases, y);
    k_combine<<<T_TOK, 256, 0, stream>>>(y, slot_of_tok, out);
}

// Round 2
// 193.939 us; speedup vs baseline: 1.1878x; 1.1878x over previous
//
#include <hip/hip_runtime.h>
#include <hip/hip_fp16.h>

#define T_TOK 1024
#define H_DIM 2048
#define I_DIM 1408
#define N_EXP 8
#define TOPK  2

using f16x8 = __attribute__((ext_vector_type(8))) _Float16;
using f16x4 = __attribute__((ext_vector_type(4))) _Float16;
using f32x4 = __attribute__((ext_vector_type(4))) float;

#define BM 128
#define BN 64
#define BK 32
#define LDSP 40   // padded K stride in halves (80 B): keeps 16B alignment for b128, <=2-way read conflicts
#define NTHR 512

// ---------------- workspace layout (bytes) ----------------
#define WS_COUNTS      0
#define WS_BASES       256
#define WS_CURSORS     512
#define WS_TOPK_E      768                       // int[2048]
#define WS_TOPK_W      (768 + 8192)              // float[2048]
#define WS_TOK_OF_SLOT 17408                     // int[3072] (padded slots)
#define WS_W_OF_SLOT   29696                     // float[3072]
#define WS_HACT        43008                     // f16[3072*1408] = 8650752 B
#define WS_NEEDED      (43008 + 8650752)

// ---------------- router ----------------
__global__ void k_zero_counts(int* counts) {
    if (threadIdx.x < N_EXP) counts[threadIdx.x] = 0;
}

__global__ void k_router(const float* __restrict__ X, const float* __restrict__ GW,
                         int* __restrict__ counts, int* __restrict__ topk_e,
                         float* __restrict__ topk_w) {
    int t = (blockIdx.x * blockDim.x + threadIdx.x) >> 6;
    int lane = threadIdx.x & 63;
    if (t >= T_TOK) return;
    float acc[N_EXP];
#pragma unroll
    for (int e = 0; e < N_EXP; ++e) acc[e] = 0.f;
    const float* xrow = X + (size_t)t * H_DIM;
    for (int h = lane; h < H_DIM; h += 64) {
        float x = xrow[h];
        const float* g = GW + (size_t)h * N_EXP;
#pragma unroll
        for (int e = 0; e < N_EXP; ++e) acc[e] = fmaf(x, g[e], acc[e]);
    }
#pragma unroll
    for (int off = 32; off > 0; off >>= 1) {
#pragma unroll
        for (int e = 0; e < N_EXP; ++e) acc[e] += __shfl_xor(acc[e], off, 64);
    }
    if (lane == 0) {
        float m = acc[0];
#pragma unroll
        for (int e = 1; e < N_EXP; ++e) m = fmaxf(m, acc[e]);
        float ex[N_EXP], s = 0.f;
#pragma unroll
        for (int e = 0; e < N_EXP; ++e) { ex[e] = expf(acc[e] - m); s += ex[e]; }
        float inv = 1.f / s;
        int e1 = 0;
#pragma unroll
        for (int e = 1; e < N_EXP; ++e) if (ex[e] > ex[e1]) e1 = e;
        int e2 = (e1 == 0) ? 1 : 0;
#pragma unroll
        for (int e = 0; e < N_EXP; ++e) if (e != e1 && ex[e] > ex[e2]) e2 = e;
        topk_e[t * 2 + 0] = e1;
        topk_e[t * 2 + 1] = e2;
        topk_w[t * 2 + 0] = ex[e1] * inv;
        topk_w[t * 2 + 1] = ex[e2] * inv;
        atomicAdd(&counts[e1], 1);
        atomicAdd(&counts[e2], 1);
    }
}

// bases padded to BM so every M-block belongs to exactly one expert
__global__ void k_prefix(const int* __restrict__ counts, int* __restrict__ bases,
                         int* __restrict__ cursors) {
    if (threadIdx.x == 0) {
        int b = 0;
        for (int e = 0; e < N_EXP; ++e) {
            bases[e] = b;
            b += ((counts[e] + BM - 1) / BM) * BM;
            cursors[e] = 0;
        }
    }
}

__global__ void k_scatter(const int* __restrict__ topk_e, const float* __restrict__ topk_w,
                          const int* __restrict__ bases, int* __restrict__ cursors,
                          int* __restrict__ tok_of_slot, float* __restrict__ w_of_slot) {
    int t = blockIdx.x * blockDim.x + threadIdx.x;
    if (t >= T_TOK) return;
    for (int j = 0; j < TOPK; ++j) {
        int e = topk_e[t * 2 + j];
        int pos = atomicAdd(&cursors[e], 1);
        int slot = bases[e] + pos;
        tok_of_slot[slot] = t;
        w_of_slot[slot] = topk_w[t * 2 + j];
    }
}

__global__ void k_zero_out(float* __restrict__ out) {
    int i = blockIdx.x * blockDim.x + threadIdx.x;
    ((float4*)out)[i] = float4{0.f, 0.f, 0.f, 0.f};
}

// ---------------- GEMM1: hact[slot, i] = silu(x[tok] . w1[e,:,i]) * w_slot ----------------
__global__ __launch_bounds__(NTHR) void k_gemm1(
    const float* __restrict__ X, const float* __restrict__ W1,
    const int* __restrict__ counts, const int* __restrict__ bases,
    const int* __restrict__ tok_of_slot, const float* __restrict__ w_of_slot,
    _Float16* __restrict__ hact) {
    __shared__ _Float16 As[2][BM][LDSP];
    __shared__ _Float16 Bs[2][BN][LDSP];

    const int e = blockIdx.z;
    const int cnt = counts[e];
    const int m0 = blockIdx.y * BM;
    if (m0 >= cnt) return;
    const int base = bases[e];
    const int n0 = blockIdx.x * BN;
    const int tid = threadIdx.x;

    // A staging: thread -> (row 0..127, 8-wide k chunk)
    const int ar = tid >> 2;
    const int akc = (tid & 3) * 8;
    const int r_eff = min(ar, cnt - m0 - 1);
    const float* arow = X + (size_t)tok_of_slot[base + m0 + r_eff] * H_DIM + akc;

    // B staging: thread -> (col n 0..63, 4 k-rows)
    const int bn = tid & 63;
    const int bkq = (tid >> 6) * 4;
    const float* bcol = W1 + (size_t)e * H_DIM * I_DIM + (size_t)bkq * I_DIM + n0 + bn;

    const int wid = tid >> 6, lane = tid & 63;
    const int wm = (wid >> 1) * 32, wn = (wid & 1) * 32;
    const int rsel = lane & 15, ksel = (lane >> 4) * 8;

    f32x4 acc[2][2] = {};
    float a_reg[8], b_reg[4];

    auto load_regs = [&](int k0) {
        *(float4*)(a_reg + 0) = *(const float4*)(arow + k0);
        *(float4*)(a_reg + 4) = *(const float4*)(arow + k0 + 4);
        const float* bp = bcol + (size_t)k0 * I_DIM;
        b_reg[0] = bp[0];
        b_reg[1] = bp[I_DIM];
        b_reg[2] = bp[2 * I_DIM];
        b_reg[3] = bp[3 * I_DIM];
    };
    auto store_lds = [&](int buf) {
        f16x8 a;
#pragma unroll
        for (int j = 0; j < 8; ++j) a[j] = (_Float16)a_reg[j];
        *(f16x8*)&As[buf][ar][akc] = a;
        f16x4 b;
#pragma unroll
        for (int j = 0; j < 4; ++j) b[j] = (_Float16)b_reg[j];
        *(f16x4*)&Bs[buf][bn][bkq] = b;
    };

    load_regs(0);
    store_lds(0);
    __syncthreads();
    const int KT = H_DIM / BK;
    for (int kt = 0; kt < KT; ++kt) {
        const int cur = kt & 1;
        if (kt + 1 < KT) load_regs((kt + 1) * BK);   // issue early (async under compute)
        f16x8 af[2], bf[2];
#pragma unroll
        for (int i = 0; i < 2; ++i)
            af[i] = *(const f16x8*)&As[cur][wm + i * 16 + rsel][ksel];
#pragma unroll
        for (int j = 0; j < 2; ++j)
            bf[j] = *(const f16x8*)&Bs[cur][wn + j * 16 + rsel][ksel];
#pragma unroll
        for (int i = 0; i < 2; ++i)
#pragma unroll
            for (int j = 0; j < 2; ++j)
                acc[i][j] = __builtin_amdgcn_mfma_f32_16x16x32_f16(af[i], bf[j], acc[i][j], 0, 0, 0);
        if (kt + 1 < KT) store_lds(cur ^ 1);         // write late (after vmcnt wait)
        __syncthreads();
    }

    const int rows = cnt - m0;
#pragma unroll
    for (int i = 0; i < 2; ++i) {
#pragma unroll
        for (int q = 0; q < 4; ++q) {
            int r = wm + i * 16 + (lane >> 4) * 4 + q;
            if (r < rows) {
                int slot = base + m0 + r;
                float w = w_of_slot[slot];
                _Float16* hrow = hact + (size_t)slot * I_DIM + n0;
#pragma unroll
                for (int j = 0; j < 2; ++j) {
                    float v = acc[i][j][q];
                    float s = v / (1.f + expf(-v)) * w;
                    hrow[wn + j * 16 + rsel] = (_Float16)s;
                }
            }
        }
    }
}

// ---------------- GEMM2: out[tok, h] += hact[slot, :] . w2[e, :, h] ----------------
__global__ __launch_bounds__(NTHR) void k_gemm2(
    const _Float16* __restrict__ hact, const float* __restrict__ W2,
    const int* __restrict__ counts, const int* __restrict__ bases,
    const int* __restrict__ tok_of_slot, float* __restrict__ out) {
    __shared__ _Float16 As[2][BM][LDSP];
    __shared__ _Float16 Bs[2][BN][LDSP];

    const int e = blockIdx.z;
    const int cnt = counts[e];
    const int m0 = blockIdx.y * BM;
    if (m0 >= cnt) return;
    const int base = bases[e];
    const int n0 = blockIdx.x * BN;
    const int tid = threadIdx.x;

    const int ar = tid >> 2;
    const int akc = (tid & 3) * 8;
    const int r_eff = min(ar, cnt - m0 - 1);
    const _Float16* arow = hact + (size_t)(base + m0 + r_eff) * I_DIM + akc;

    const int bn = tid & 63;
    const int bkq = (tid >> 6) * 4;
    const float* bcol = W2 + (size_t)e * I_DIM * H_DIM + (size_t)bkq * H_DIM + n0 + bn;

    const int wid = tid >> 6, lane = tid & 63;
    const int wm = (wid >> 1) * 32, wn = (wid & 1) * 32;
    const int rsel = lane & 15, ksel = (lane >> 4) * 8;

    f32x4 acc[2][2] = {};
    f16x8 a_reg;
    float b_reg[4];

    auto load_regs = [&](int k0) {
        a_reg = *(const f16x8*)(arow + k0);
        const float* bp = bcol + (size_t)k0 * H_DIM;
        b_reg[0] = bp[0];
        b_reg[1] = bp[H_DIM];
        b_reg[2] = bp[2 * H_DIM];
        b_reg[3] = bp[3 * H_DIM];
    };
    auto store_lds = [&](int buf) {
        *(f16x8*)&As[buf][ar][akc] = a_reg;
        f16x4 b;
#pragma unroll
        for (int j = 0; j < 4; ++j) b[j] = (_Float16)b_reg[j];
        *(f16x4*)&Bs[buf][bn][bkq] = b;
    };

    load_regs(0);
    store_lds(0);
    __syncthreads();
    const int KT = I_DIM / BK;
    for (int kt = 0; kt < KT; ++kt) {
        const int cur = kt & 1;
        if (kt + 1 < KT) load_regs((kt + 1) * BK);
        f16x8 af[2], bf[2];
#pragma unroll
        for (int i = 0; i < 2; ++i)
            af[i] = *(const f16x8*)&As[cur][wm + i * 16 + rsel][ksel];
#pragma unroll
        for (int j = 0; j < 2; ++j)
            bf[j] = *(const f16x8*)&Bs[cur][wn + j * 16 + rsel][ksel];
#pragma unroll
        for (int i = 0; i < 2; ++i)
#pragma unroll
            for (int j = 0; j < 2; ++j)
                acc[i][j] = __builtin_amdgcn_mfma_f32_16x16x32_f16(af[i], bf[j], acc[i][j], 0, 0, 0);
        if (kt + 1 < KT) store_lds(cur ^ 1);
        __syncthreads();
    }

    const int rows = cnt - m0;
#pragma unroll
    for (int i = 0; i < 2; ++i) {
#pragma unroll
        for (int q = 0; q < 4; ++q) {
            int r = wm + i * 16 + (lane >> 4) * 4 + q;
            if (r < rows) {
                int slot = base + m0 + r;
                int tok = tok_of_slot[slot];
                float* orow = out + (size_t)tok * H_DIM + n0;
#pragma unroll
                for (int j = 0; j < 2; ++j)
                    atomicAdd(&orow[wn + j * 16 + rsel], acc[i][j][q]);
            }
        }
    }
}

extern "C" void kernel_launch(void* const* d_in, const int* in_sizes, int n_in,
                              void* d_out, int out_size, void* d_ws, size_t ws_size,
                              hipStream_t stream) {
    const float* X  = (const float*)d_in[0];
    const float* GW = (const float*)d_in[1];
    const float* W1 = (const float*)d_in[2];
    const float* W2 = (const float*)d_in[3];
    float* out = (float*)d_out;
    char* ws = (char*)d_ws;
    if (ws_size < (size_t)WS_NEEDED) return;

    int*   counts      = (int*)(ws + WS_COUNTS);
    int*   bases       = (int*)(ws + WS_BASES);
    int*   cursors     = (int*)(ws + WS_CURSORS);
    int*   topk_e      = (int*)(ws + WS_TOPK_E);
    float* topk_w      = (float*)(ws + WS_TOPK_W);
    int*   tok_of_slot = (int*)(ws + WS_TOK_OF_SLOT);
    float* w_of_slot   = (float*)(ws + WS_W_OF_SLOT);
    _Float16* hact     = (_Float16*)(ws + WS_HACT);

    k_zero_counts<<<1, 64, 0, stream>>>(counts);
    k_router<<<T_TOK / 4, 256, 0, stream>>>(X, GW, counts, topk_e, topk_w);
    k_prefix<<<1, 64, 0, stream>>>(counts, bases, cursors);
    k_scatter<<<T_TOK / 256, 256, 0, stream>>>(topk_e, topk_w, bases, cursors,
                                               tok_of_slot, w_of_slot);
    k_zero_out<<<(T_TOK * H_DIM / 4) / 256, 256, 0, stream>>>(out);
    k_gemm1<<<dim3(I_DIM / BN, T_TOK / BM, N_EXP), NTHR, 0, stream>>>(
        X, W1, counts, bases, tok_of_slot, w_of_slot, hact);
    k_gemm2<<<dim3(H_DIM / BN, T_TOK / BM, N_EXP), NTHR, 0, stream>>>(
        hact, W2, counts, bases, tok_of_slot, out);
}

// Round 3
// 166.121 us; speedup vs baseline: 1.3867x; 1.1675x over previous
//
#include <hip/hip_runtime.h>
#include <hip/hip_fp16.h>

#define T_TOK 1024
#define H_DIM 2048
#define I_DIM 1408
#define N_EXP 8
#define TOPK  2

using f16x8 = __attribute__((ext_vector_type(8))) _Float16;
using f32x4 = __attribute__((ext_vector_type(4))) float;

#define BM 128
#define BN 64
#define BK 64
#define NTHR 512

// ---------------- workspace layout (bytes) ----------------
#define WS_COUNTS      0
#define WS_BASES       256
#define WS_CURSORS     512
#define WS_TOPK_E      768                       // int[2048]
#define WS_TOPK_W      (768 + 8192)              // float[2048]
#define WS_TOK_OF_SLOT 17408                     // int[3072] (padded slots)
#define WS_W_OF_SLOT   29696                     // float[3072]
#define WS_HACT        43008                     // f16[3072*1408] = 8650752 B
#define WS_NEEDED      (43008 + 8650752)

// ---------------- router ----------------
__global__ void k_router(const float* __restrict__ X, const float* __restrict__ GW,
                         int* __restrict__ counts, int* __restrict__ topk_e,
                         float* __restrict__ topk_w) {
    int t = (blockIdx.x * blockDim.x + threadIdx.x) >> 6;
    int lane = threadIdx.x & 63;
    if (t >= T_TOK) return;
    float acc[N_EXP];
#pragma unroll
    for (int e = 0; e < N_EXP; ++e) acc[e] = 0.f;
    const float* xrow = X + (size_t)t * H_DIM;
    for (int h = lane; h < H_DIM; h += 64) {
        float x = xrow[h];
        const float* g = GW + (size_t)h * N_EXP;
#pragma unroll
        for (int e = 0; e < N_EXP; ++e) acc[e] = fmaf(x, g[e], acc[e]);
    }
#pragma unroll
    for (int off = 32; off > 0; off >>= 1) {
#pragma unroll
        for (int e = 0; e < N_EXP; ++e) acc[e] += __shfl_xor(acc[e], off, 64);
    }
    if (lane == 0) {
        float m = acc[0];
#pragma unroll
        for (int e = 1; e < N_EXP; ++e) m = fmaxf(m, acc[e]);
        float ex[N_EXP], s = 0.f;
#pragma unroll
        for (int e = 0; e < N_EXP; ++e) { ex[e] = expf(acc[e] - m); s += ex[e]; }
        float inv = 1.f / s;
        int e1 = 0;
#pragma unroll
        for (int e = 1; e < N_EXP; ++e) if (ex[e] > ex[e1]) e1 = e;
        int e2 = (e1 == 0) ? 1 : 0;
#pragma unroll
        for (int e = 0; e < N_EXP; ++e) if (e != e1 && ex[e] > ex[e2]) e2 = e;
        topk_e[t * 2 + 0] = e1;
        topk_e[t * 2 + 1] = e2;
        topk_w[t * 2 + 0] = ex[e1] * inv;
        topk_w[t * 2 + 1] = ex[e2] * inv;
        atomicAdd(&counts[e1], 1);
        atomicAdd(&counts[e2], 1);
    }
}

// bases padded to BM so every M-block belongs to exactly one expert
__global__ void k_prefix(const int* __restrict__ counts, int* __restrict__ bases,
                         int* __restrict__ cursors) {
    if (threadIdx.x == 0) {
        int b = 0;
        for (int e = 0; e < N_EXP; ++e) {
            bases[e] = b;
            b += ((counts[e] + BM - 1) / BM) * BM;
            cursors[e] = 0;
        }
    }
}

__global__ void k_scatter(const int* __restrict__ topk_e, const float* __restrict__ topk_w,
                          const int* __restrict__ bases, int* __restrict__ cursors,
                          int* __restrict__ tok_of_slot, float* __restrict__ w_of_slot) {
    int t = blockIdx.x * blockDim.x + threadIdx.x;
    if (t >= T_TOK) return;
    for (int j = 0; j < TOPK; ++j) {
        int e = topk_e[t * 2 + j];
        int pos = atomicAdd(&cursors[e], 1);
        int slot = bases[e] + pos;
        tok_of_slot[slot] = t;
        w_of_slot[slot] = topk_w[t * 2 + j];
    }
}

// ---------------- GEMM1: hact[slot, i] = silu(x[tok] . w1[e,:,i]) * w_slot ----------------
// LDS layout: [row][8 slots of 16B], slot XOR-swizzled by (row&7). No padding.
__global__ __launch_bounds__(NTHR, 4) void k_gemm1(
    const float* __restrict__ X, const float* __restrict__ W1,
    const int* __restrict__ counts, const int* __restrict__ bases,
    const int* __restrict__ tok_of_slot, const float* __restrict__ w_of_slot,
    _Float16* __restrict__ hact) {
    __shared__ _Float16 As[2][BM][BK];
    __shared__ _Float16 Bs[2][BN][BK];

    const int e = blockIdx.z;
    const int cnt = counts[e];
    const int m0 = blockIdx.y * BM;
    if (m0 >= cnt) return;
    const int base = bases[e];
    const int n0 = blockIdx.x * BN;
    const int tid = threadIdx.x;

    // A staging: thread -> (row 0..127, 16-float k chunk)
    const int ar = tid >> 2;
    const int ac2 = (tid & 3) * 2;              // first 8-half slot index (0,2,4,6)
    const int r_eff = min(ar, cnt - m0 - 1);
    const float* arow = X + (size_t)tok_of_slot[base + m0 + r_eff] * H_DIM + (tid & 3) * 16;

    // B staging: thread -> (col n 0..63, 8 k-rows)
    const int bn = tid & 63;
    const int bc = tid >> 6;                    // slot index 0..7
    const float* bcol = W1 + (size_t)e * H_DIM * I_DIM + (size_t)(bc * 8) * I_DIM + n0 + bn;

    const int wid = tid >> 6, lane = tid & 63;
    const int wm = (wid >> 1) * 32, wn = (wid & 1) * 32;
    const int rsel = lane & 15, kq = lane >> 4;

    f32x4 acc[2][2] = {};

    float4 aR0[4]; float bR0[8];
    float4 aR1[4]; float bR1[8];

#define LOAD1(aR, bR, k0)                                              \
    do {                                                               \
        aR[0] = *(const float4*)(arow + (k0));                         \
        aR[1] = *(const float4*)(arow + (k0) + 4);                     \
        aR[2] = *(const float4*)(arow + (k0) + 8);                     \
        aR[3] = *(const float4*)(arow + (k0) + 12);                    \
        const float* bp = bcol + (size_t)(k0) * I_DIM;                 \
        _Pragma("unroll") for (int j = 0; j < 8; ++j)                  \
            bR[j] = bp[(size_t)j * I_DIM];                             \
    } while (0)

#define STORE1(buf, aR, bR)                                            \
    do {                                                               \
        f16x8 p0, p1;                                                  \
        _Pragma("unroll") for (int j = 0; j < 4; ++j) {                \
            p0[j]     = (_Float16)aR[0][j];                            \
            p0[j + 4] = (_Float16)aR[1][j];                            \
            p1[j]     = (_Float16)aR[2][j];                            \
            p1[j + 4] = (_Float16)aR[3][j];                            \
        }                                                              \
        *(f16x8*)&As[buf][ar][((ac2) ^ (ar & 7)) * 8] = p0;            \
        *(f16x8*)&As[buf][ar][((ac2 + 1) ^ (ar & 7)) * 8] = p1;        \
        f16x8 q;                                                       \
        _Pragma("unroll") for (int j = 0; j < 8; ++j)                  \
            q[j] = (_Float16)bR[j];                                    \
        *(f16x8*)&Bs[buf][bn][(bc ^ (bn & 7)) * 8] = q;                \
    } while (0)

#define COMPUTE(buf)                                                   \
    do {                                                               \
        _Pragma("unroll") for (int ks = 0; ks < 2; ++ks) {             \
            f16x8 af[2], bf[2];                                        \
            _Pragma("unroll") for (int i = 0; i < 2; ++i) {            \
                int r = wm + i * 16 + rsel;                            \
                af[i] = *(const f16x8*)&As[buf][r][((kq + 4 * ks) ^ (r & 7)) * 8]; \
            }                                                          \
            _Pragma("unroll") for (int j = 0; j < 2; ++j) {            \
                int r = wn + j * 16 + rsel;                            \
                bf[j] = *(const f16x8*)&Bs[buf][r][((kq + 4 * ks) ^ (r & 7)) * 8]; \
            }                                                          \
            _Pragma("unroll") for (int i = 0; i < 2; ++i)              \
                _Pragma("unroll") for (int j = 0; j < 2; ++j)          \
                    acc[i][j] = __builtin_amdgcn_mfma_f32_16x16x32_f16(af[i], bf[j], acc[i][j], 0, 0, 0); \
        }                                                              \
    } while (0)

    const int KT = H_DIM / BK;   // 32, even
    LOAD1(aR0, bR0, 0);
    STORE1(0, aR0, bR0);
    LOAD1(aR0, bR0, BK);         // set0 now holds tile 1
    __syncthreads();
    for (int kt = 0; kt < KT; kt += 2) {
        // iter kt: cur=0, X=set0 (holds kt+1), Y=set1 (free)
        if (kt + 2 < KT) LOAD1(aR1, bR1, (kt + 2) * BK);
        COMPUTE(0);
        if (kt + 1 < KT) STORE1(1, aR0, bR0);
        __syncthreads();
        // iter kt+1: cur=1, X=set1 (holds kt+2), Y=set0 (free)
        if (kt + 3 < KT) LOAD1(aR0, bR0, (kt + 3) * BK);
        if (kt + 1 < KT) {
            COMPUTE(1);
            if (kt + 2 < KT) STORE1(0, aR1, bR1);
            __syncthreads();
        }
    }
#undef LOAD1
#undef STORE1
#undef COMPUTE

    const int rows = cnt - m0;
#pragma unroll
    for (int i = 0; i < 2; ++i) {
#pragma unroll
        for (int q = 0; q < 4; ++q) {
            int r = wm + i * 16 + kq * 4 + q;
            if (r < rows) {
                int slot = base + m0 + r;
                float w = w_of_slot[slot];
                _Float16* hrow = hact + (size_t)slot * I_DIM + n0;
#pragma unroll
                for (int j = 0; j < 2; ++j) {
                    float v = acc[i][j][q];
                    float s = v / (1.f + expf(-v)) * w;
                    hrow[wn + j * 16 + rsel] = (_Float16)s;
                }
            }
        }
    }
}

// ---------------- GEMM2: out[tok, h] += hact[slot, :] . w2[e, :, h] ----------------
__global__ __launch_bounds__(NTHR, 4) void k_gemm2(
    const _Float16* __restrict__ hact, const float* __restrict__ W2,
    const int* __restrict__ counts, const int* __restrict__ bases,
    const int* __restrict__ tok_of_slot, float* __restrict__ out) {
    __shared__ _Float16 As[2][BM][BK];
    __shared__ _Float16 Bs[2][BN][BK];

    const int e = blockIdx.z;
    const int cnt = counts[e];
    const int m0 = blockIdx.y * BM;
    if (m0 >= cnt) return;
    const int base = bases[e];
    const int n0 = blockIdx.x * BN;
    const int tid = threadIdx.x;

    const int ar = tid >> 2;
    const int ac2 = (tid & 3) * 2;
    const int r_eff = min(ar, cnt - m0 - 1);
    const _Float16* arow = hact + (size_t)(base + m0 + r_eff) * I_DIM + (tid & 3) * 16;

    const int bn = tid & 63;
    const int bc = tid >> 6;
    const float* bcol = W2 + (size_t)e * I_DIM * H_DIM + (size_t)(bc * 8) * H_DIM + n0 + bn;

    const int wid = tid >> 6, lane = tid & 63;
    const int wm = (wid >> 1) * 32, wn = (wid & 1) * 32;
    const int rsel = lane & 15, kq = lane >> 4;

    f32x4 acc[2][2] = {};

    f16x8 aR0[2]; float bR0[8];
    f16x8 aR1[2]; float bR1[8];

#define LOAD2(aR, bR, k0)                                              \
    do {                                                               \
        aR[0] = *(const f16x8*)(arow + (k0));                          \
        aR[1] = *(const f16x8*)(arow + (k0) + 8);                      \
        const float* bp = bcol + (size_t)(k0) * H_DIM;                 \
        _Pragma("unroll") for (int j = 0; j < 8; ++j)                  \
            bR[j] = bp[(size_t)j * H_DIM];                             \
    } while (0)

#define STORE2(buf, aR, bR)                                            \
    do {                                                               \
        *(f16x8*)&As[buf][ar][((ac2) ^ (ar & 7)) * 8] = aR[0];         \
        *(f16x8*)&As[buf][ar][((ac2 + 1) ^ (ar & 7)) * 8] = aR[1];     \
        f16x8 q;                                                       \
        _Pragma("unroll") for (int j = 0; j < 8; ++j)                  \
            q[j] = (_Float16)bR[j];                                    \
        *(f16x8*)&Bs[buf][bn][(bc ^ (bn & 7)) * 8] = q;                \
    } while (0)

#define COMPUTE2(buf)                                                  \
    do {                                                               \
        _Pragma("unroll") for (int ks = 0; ks < 2; ++ks) {             \
            f16x8 af[2], bf[2];                                        \
            _Pragma("unroll") for (int i = 0; i < 2; ++i) {            \
                int r = wm + i * 16 + rsel;                            \
                af[i] = *(const f16x8*)&As[buf][r][((kq + 4 * ks) ^ (r & 7)) * 8]; \
            }                                                          \
            _Pragma("unroll") for (int j = 0; j < 2; ++j) {            \
                int r = wn + j * 16 + rsel;                            \
                bf[j] = *(const f16x8*)&Bs[buf][r][((kq + 4 * ks) ^ (r & 7)) * 8]; \
            }                                                          \
            _Pragma("unroll") for (int i = 0; i < 2; ++i)              \
                _Pragma("unroll") for (int j = 0; j < 2; ++j)          \
                    acc[i][j] = __builtin_amdgcn_mfma_f32_16x16x32_f16(af[i], bf[j], acc[i][j], 0, 0, 0); \
        }                                                              \
    } while (0)

    const int KT = I_DIM / BK;   // 22, even
    LOAD2(aR0, bR0, 0);
    STORE2(0, aR0, bR0);
    LOAD2(aR0, bR0, BK);
    __syncthreads();
    for (int kt = 0; kt < KT; kt += 2) {
        if (kt + 2 < KT) LOAD2(aR1, bR1, (kt + 2) * BK);
        COMPUTE2(0);
        if (kt + 1 < KT) STORE2(1, aR0, bR0);
        __syncthreads();
        if (kt + 3 < KT) LOAD2(aR0, bR0, (kt + 3) * BK);
        if (kt + 1 < KT) {
            COMPUTE2(1);
            if (kt + 2 < KT) STORE2(0, aR1, bR1);
            __syncthreads();
        }
    }
#undef LOAD2
#undef STORE2
#undef COMPUTE2

    const int rows = cnt - m0;
#pragma unroll
    for (int i = 0; i < 2; ++i) {
#pragma unroll
        for (int q = 0; q < 4; ++q) {
            int r = wm + i * 16 + kq * 4 + q;
            if (r < rows) {
                int slot = base + m0 + r;
                int tok = tok_of_slot[slot];
                float* orow = out + (size_t)tok * H_DIM + n0;
#pragma unroll
                for (int j = 0; j < 2; ++j)
                    atomicAdd(&orow[wn + j * 16 + rsel], acc[i][j][q]);
            }
        }
    }
}

extern "C" void kernel_launch(void* const* d_in, const int* in_sizes, int n_in,
                              void* d_out, int out_size, void* d_ws, size_t ws_size,
                              hipStream_t stream) {
    const float* X  = (const float*)d_in[0];
    const float* GW = (const float*)d_in[1];
    const float* W1 = (const float*)d_in[2];
    const float* W2 = (const float*)d_in[3];
    float* out = (float*)d_out;
    char* ws = (char*)d_ws;
    if (ws_size < (size_t)WS_NEEDED) return;

    int*   counts      = (int*)(ws + WS_COUNTS);
    int*   bases       = (int*)(ws + WS_BASES);
    int*   cursors     = (int*)(ws + WS_CURSORS);
    int*   topk_e      = (int*)(ws + WS_TOPK_E);
    float* topk_w      = (float*)(ws + WS_TOPK_W);
    int*   tok_of_slot = (int*)(ws + WS_TOK_OF_SLOT);
    float* w_of_slot   = (float*)(ws + WS_W_OF_SLOT);
    _Float16* hact     = (_Float16*)(ws + WS_HACT);

    hipMemsetAsync(counts, 0, N_EXP * sizeof(int), stream);
    k_router<<<T_TOK / 4, 256, 0, stream>>>(X, GW, counts, topk_e, topk_w);
    k_prefix<<<1, 64, 0, stream>>>(counts, bases, cursors);
    k_scatter<<<T_TOK / 256, 256, 0, stream>>>(topk_e, topk_w, bases, cursors,
                                               tok_of_slot, w_of_slot);
    hipMemsetAsync(out, 0, (size_t)T_TOK * H_DIM * sizeof(float), stream);
    k_gemm1<<<dim3(I_DIM / BN, T_TOK / BM, N_EXP), NTHR, 0, stream>>>(
        X, W1, counts, bases, tok_of_slot, w_of_slot, hact);
    k_gemm2<<<dim3(H_DIM / BN, T_TOK / BM, N_EXP), NTHR, 0, stream>>>(
        hact, W2, counts, bases, tok_of_slot, out);
}